// Round 9
// baseline (5629.746 us; speedup 1.0000x reference)
//
#include <hip/hip_runtime.h>
#include <cstddef>
#include <cstdint>

using f32x4  = __attribute__((ext_vector_type(4))) float;
using bf16x8 = __attribute__((ext_vector_type(8))) short;
using u16x4  = __attribute__((ext_vector_type(4))) unsigned short;
typedef unsigned short u16;

#define LMDA 0.005f

__device__ __forceinline__ u16 f2bf(float f) {
    union { float f; uint32_t u; } v; v.f = f;
    return (u16)((v.u + 0x7FFFu + ((v.u >> 16) & 1u)) >> 16);
}
__device__ __forceinline__ float bf2f(u16 b) {
    union { uint32_t u; float f; } v; v.u = ((uint32_t)b) << 16;
    return v.f;
}
__device__ __forceinline__ void split2(float x, u16& h, u16& l) {
    h = f2bf(x); l = f2bf(x - bf2f(h));
}
__device__ __forceinline__ float sthr(float x) {
    float ax = fabsf(x) - LMDA;
    return ax > 0.0f ? copysignf(ax, x) : 0.0f;
}

// async 16B global -> LDS (HW writes lane l at ldsbase + l*16)
__device__ __forceinline__ void gload16(const u16* g, u16* l) {
    __builtin_amdgcn_global_load_lds(
        (const __attribute__((address_space(1))) unsigned int*)(const void*)g,
        (__attribute__((address_space(3))) unsigned int*)(void*)l, 16, 0, 0);
}

// ---------------------------------------------------------------------------
// ITERATION KERNEL: tile 128x128, FULL K=1024, grid 128 (16 tr x 8 tc).
// Rationale: all prior rounds were L3-supply-bound (~200-256 MB staged/iter at
// ~6-8 TB/s = the invariant 30-33 us). 128^2 tiles halve staged bytes to
// 128 MB/iter and give MFMA:ds_read ratio 3.
// 4 waves (2mr x 2nc), wavetile 64x64 = 4x4 frags of 16x16x32, 3 products:
//   acc = Wh*Rh + Wl*Rh + Wh*Rl   (swapped operands: mfma(W-frag, R-frag),
//   D col(lane&15)=m-local, row(lg*4+e)=n-local -> contiguous n stores)
// BK=32, 32 k-steps, LDS 3 x 32KB fragment-ordered 1KB chunks (lane*16B =
// global_load_lds linear dest + conflict-free ds_read_b128).
// Counted-vmcnt pipeline, depth 2: at step s top, wait vmcnt(8) (stage s done,
// stage s+1's 8 loads in flight), barrier, issue stage s+2 into buf (s+2)%3
// (only read at step s+2, gated by its own vmcnt). Hides L3 latency.
// OM 0: R' = split(st(acc + Cs))  (ISTA step)    OM 1: OutF = acc  (final)
// ---------------------------------------------------------------------------
template<int OM>
__global__ __launch_bounds__(256)
void gemm_big(const u16* __restrict__ Rh, const u16* __restrict__ Rl,
              const u16* __restrict__ Wh, const u16* __restrict__ Wl,
              const float* __restrict__ Cs,
              u16* __restrict__ Nh, u16* __restrict__ Nl,
              float* __restrict__ OutF)
{
    __shared__ __align__(16) u16 S[3][32 * 512];   // 3 x 32 KiB

    // XCD-aware bijective swizzle (128 % 8 == 0): each XCD gets 16
    // consecutive tiles = 2 full tile-rows -> per-XCD unique R band minimal.
    const int fid = blockIdx.x;
    const int sid = (fid & 7) * 16 + (fid >> 3);
    const int tr = sid >> 3;              // 0..15
    const int tc = sid & 7;               // 0..7
    const int row0 = tr << 7;
    const int col0 = tc << 7;

    const int tid  = threadIdx.x;
    const int lane = tid & 63;
    const int w    = tid >> 6;            // 0..3
    const int mr   = w >> 1;              // m-half
    const int nc   = w & 1;               // n-half
    const int l15  = lane & 15;
    const int lg   = lane >> 4;           // 0..3
    const int l8   = lane << 3;           // u16 offset of lane's 16B

    // ---- staging: 32 chunks of 1KB per step (16 R + 16 W), 8 per wave ----
    // chunk c: mat=c>>4 (0:R from row0, 1:W from col0), h=(c>>3)&1, g=c&7
    // lane l <- M_h[base + g*16 + (l&15)][k0 + (l>>4)*8 .. +8)
    const u16* gsrc[8];
    int loff[8];
    #pragma unroll
    for (int t = 0; t < 8; ++t) {
        const int c = (w << 3) + t;
        const int h = (c >> 3) & 1;
        const int g = c & 7;
        const u16* base;
        int r;
        if (c < 16) { base = h ? Rl : Rh; r = row0 + (g << 4) + l15; }
        else        { base = h ? Wl : Wh; r = col0 + (g << 4) + l15; }
        gsrc[t] = base + ((size_t)r << 10) + (lg << 3);
        loff[t] = (c << 9) + l8;
    }
    auto stage = [&](int b, int k) {
        #pragma unroll
        for (int t = 0; t < 8; ++t)
            gload16(gsrc[t] + k, &S[b][loff[t]]);
    };

    f32x4 acc[4][4] = {};   // [ni][mj]

    stage(0, 0);
    stage(1, 32);

    int cur = 0;
    for (int s = 0; s < 32; ++s) {
        if (s < 31) asm volatile("s_waitcnt vmcnt(8)" ::: "memory");
        else        asm volatile("s_waitcnt vmcnt(0)" ::: "memory");
        __builtin_amdgcn_s_barrier();
        asm volatile("" ::: "memory");
        if (s + 2 < 32) {
            int nb = cur + 2; if (nb >= 3) nb -= 3;
            stage(nb, (s + 2) << 5);
        }

        const u16* Sb = S[cur];
        bf16x8 rh[4], rl[4], wh[4], wl[4];
        #pragma unroll
        for (int i = 0; i < 4; ++i) {
            const int gm = (mr << 2) + i;          // R chunk g
            const int gn = (nc << 2) + i;          // W chunk g
            rh[i] = *(const bf16x8*)&Sb[((0  + gm) << 9) + l8];
            rl[i] = *(const bf16x8*)&Sb[((8  + gm) << 9) + l8];
            wh[i] = *(const bf16x8*)&Sb[((16 + gn) << 9) + l8];
            wl[i] = *(const bf16x8*)&Sb[((24 + gn) << 9) + l8];
        }
        #pragma unroll
        for (int ni = 0; ni < 4; ++ni)
            #pragma unroll
            for (int mj = 0; mj < 4; ++mj) {
                acc[ni][mj] = __builtin_amdgcn_mfma_f32_16x16x32_bf16(wh[ni], rh[mj], acc[ni][mj], 0, 0, 0);
                acc[ni][mj] = __builtin_amdgcn_mfma_f32_16x16x32_bf16(wl[ni], rh[mj], acc[ni][mj], 0, 0, 0);
                acc[ni][mj] = __builtin_amdgcn_mfma_f32_16x16x32_bf16(wh[ni], rl[mj], acc[ni][mj], 0, 0, 0);
            }
        asm volatile("" ::: "memory");
        ++cur; if (cur >= 3) cur -= 3;
    }

    // ---- fused epilogue (swapped-operand D layout: col=m-local, row=n-local)
    #pragma unroll
    for (int ni = 0; ni < 4; ++ni) {
        #pragma unroll
        for (int mj = 0; mj < 4; ++mj) {
            const int m  = row0 + (mr << 6) + (mj << 4) + l15;
            const int n0 = col0 + (nc << 6) + (ni << 4) + (lg << 2);
            const size_t idx = ((size_t)m << 10) + n0;
            if (OM == 0) {
                const f32x4 cs = *(const f32x4*)&Cs[idx];
                u16x4 hv, lv;
                #pragma unroll
                for (int e = 0; e < 4; ++e) {
                    u16 hh, ll; split2(sthr(acc[ni][mj][e] + cs[e]), hh, ll);
                    hv[e] = hh; lv[e] = ll;
                }
                *(u16x4*)&Nh[idx] = hv;
                *(u16x4*)&Nl[idx] = lv;
            } else {
                *(f32x4*)&OutF[idx] = acc[ni][mj];
            }
        }
    }
}

// ---------------------------------------------------------------------------
// PROLOGUE GEMM (round-5, passing): fused-3 split-bf16 NT GEMM + epilogues.
// EPI 1: OutF = 0.2*acc ; R = split(st(OutF))   (Csc and R1)
// EPI 2: OutH/L = split(I - 0.2*acc)            (W)
// ---------------------------------------------------------------------------
template<int EPI>
__global__ __launch_bounds__(512, 2)
void gemm_ista(const u16* __restrict__ Ah, const u16* __restrict__ Al,
               const u16* __restrict__ Bh, const u16* __restrict__ Bl,
               int Nt,
               const float* __restrict__ Cs, float* __restrict__ OutF,
               u16* __restrict__ OutH, u16* __restrict__ OutL)
{
    __shared__ __align__(16) u16 S[3][48 * 512];   // 144 KiB

    const int nwg = gridDim.x;
    const int fid = blockIdx.x;
    const int sid = (fid & 7) * (nwg >> 3) + (fid >> 3);
    const int row0 = (sid / Nt) << 7;
    const int col0 = (sid % Nt) << 6;

    const int tid  = threadIdx.x;
    const int lane = tid & 63;
    const int w    = tid >> 6;
    const int mr = w >> 2, nc = (w >> 1) & 1, ks = w & 1;

    const u16* gb[6];
    int cf[6];
    #pragma unroll
    for (int t = 0; t < 6; ++t) {
        const int c = w * 6 + t;
        const u16* base; int r; int kss;
        if (c < 32) {
            const int h = (c >> 4) & 1; kss = (c >> 3) & 1;
            base = h ? Al : Ah;
            r = row0 + ((c & 7) << 4) + (lane & 15);
        } else {
            const int cb = c - 32;
            const int h = (cb >> 3) & 1; kss = (cb >> 2) & 1;
            base = h ? Bl : Bh;
            r = col0 + ((cb & 3) << 4) + (lane & 15);
        }
        gb[t] = base + ((size_t)r << 10) + (kss << 5) + ((lane >> 4) << 3);
        cf[t] = c << 9;
    }
    auto stage = [&](int b, int koff) {
        #pragma unroll
        for (int t = 0; t < 6; ++t)
            gload16(gb[t] + koff, &S[b][cf[t]]);
    };

    f32x4 acc[4][2] = {};

    stage(0, 0);
    stage(1, 64);

    #pragma unroll
    for (int s = 0; s < 16; ++s) {
        if (s <= 14) asm volatile("s_waitcnt vmcnt(6)" ::: "memory");
        else         asm volatile("s_waitcnt vmcnt(0)" ::: "memory");
        __builtin_amdgcn_s_barrier();
        asm volatile("" ::: "memory");
        if (s + 2 < 16) stage((s + 2) % 3, (s + 2) << 6);

        const u16* Sb = S[s % 3];
        const int ab = (ks << 3) + (mr << 2);
        const int bb = 32 + (ks << 2) + (nc << 1);
        bf16x8 ah[4], al[4], bh[2], bl[2];
        #pragma unroll
        for (int i = 0; i < 4; ++i) {
            ah[i] = *(const bf16x8*)&Sb[(ab + i)      * 512 + (lane << 3)];
            al[i] = *(const bf16x8*)&Sb[(ab + 16 + i) * 512 + (lane << 3)];
        }
        #pragma unroll
        for (int j = 0; j < 2; ++j) {
            bh[j] = *(const bf16x8*)&Sb[(bb + j)     * 512 + (lane << 3)];
            bl[j] = *(const bf16x8*)&Sb[(bb + 8 + j) * 512 + (lane << 3)];
        }
        #pragma unroll
        for (int i = 0; i < 4; ++i)
            #pragma unroll
            for (int j = 0; j < 2; ++j)
                acc[i][j] = __builtin_amdgcn_mfma_f32_16x16x32_bf16(ah[i], bh[j], acc[i][j], 0, 0, 0);
        #pragma unroll
        for (int i = 0; i < 4; ++i)
            #pragma unroll
            for (int j = 0; j < 2; ++j)
                acc[i][j] = __builtin_amdgcn_mfma_f32_16x16x32_bf16(al[i], bh[j], acc[i][j], 0, 0, 0);
        #pragma unroll
        for (int i = 0; i < 4; ++i)
            #pragma unroll
            for (int j = 0; j < 2; ++j)
                acc[i][j] = __builtin_amdgcn_mfma_f32_16x16x32_bf16(ah[i], bl[j], acc[i][j], 0, 0, 0);
        asm volatile("" ::: "memory");
    }

    __syncthreads();
    f32x4* red = (f32x4*)&S[0][0];
    const int wquad = (mr << 1) + nc;
    #pragma unroll
    for (int ih = 0; ih < 2; ++ih) {
        #pragma unroll
        for (int j = 0; j < 2; ++j) {
            const int isrc = ks ? ih : (2 + ih);
            const int slot = ((((wquad << 1) | ks) << 2) | (ih << 1) | j);
            red[slot * 64 + lane] = acc[isrc][j];
        }
    }
    __syncthreads();

    const int gr0 = row0 + (mr << 6) + ((lane >> 4) << 2);
    const int gc  = col0 + (nc << 5) + (lane & 15);
    #pragma unroll
    for (int ih = 0; ih < 2; ++ih) {
        #pragma unroll
        for (int j = 0; j < 2; ++j) {
            const int i    = ks ? (2 + ih) : ih;
            const int slot = ((((wquad << 1) | (ks ^ 1)) << 2) | (ih << 1) | j);
            f32x4 sum = acc[i][j] + red[slot * 64 + lane];
            #pragma unroll
            for (int e = 0; e < 4; ++e) {
                const int grow = gr0 + (i << 4) + e;
                const int gcol = gc + (j << 4);
                const size_t idx = ((size_t)grow << 10) + gcol;
                const float p = sum[e];
                if (EPI == 1) {
                    float f = 0.2f * p;
                    OutF[idx] = f;
                    u16 h, l; split2(sthr(f), h, l);
                    OutH[idx] = h; OutL[idx] = l;
                } else {
                    float x = (grow == gcol ? 1.0f : 0.0f) - 0.2f * p;
                    u16 h, l; split2(x, h, l);
                    OutH[idx] = h; OutL[idx] = l;
                }
            }
        }
    }
}

// fp32 -> (hi, lo) bf16 pair, elementwise
__global__ void k_split(const float* __restrict__ in, u16* __restrict__ hi,
                        u16* __restrict__ lo, int n)
{
    int i = blockIdx.x * 256 + threadIdx.x;
    if (i < n) { u16 h, l; split2(in[i], h, l); hi[i] = h; lo[i] = l; }
}

// Ut[j][k] = U[k][j] as bf16 pair (32x32 LDS tile, padded)
__global__ __launch_bounds__(256)
void k_transpose_split(const float* __restrict__ in, u16* __restrict__ hi,
                       u16* __restrict__ lo)
{
    __shared__ float t[32][33];
    const int bx = blockIdx.x, by = blockIdx.y;
    const int lx = threadIdx.x & 31, ly = threadIdx.x >> 5;
    #pragma unroll
    for (int rr = 0; rr < 4; ++rr) {
        int r = ly * 4 + rr;
        t[r][lx] = in[(size_t)(by * 32 + r) * 1024 + bx * 32 + lx];
    }
    __syncthreads();
    #pragma unroll
    for (int rr = 0; rr < 4; ++rr) {
        int r = ly * 4 + rr;
        u16 h, l; split2(t[lx][r], h, l);
        size_t idx = (size_t)(bx * 32 + r) * 1024 + by * 32 + lx;
        hi[idx] = h; lo[idx] = l;
    }
}

extern "C" void kernel_launch(void* const* d_in, const int* in_sizes, int n_in,
                              void* d_out, int out_size, void* d_ws, size_t ws_size,
                              hipStream_t stream) {
    const float* img = (const float*)d_in[0];   // (2048, 1024) fp32
    const float* U   = (const float*)d_in[1];   // (1024, 1024) fp32
    float* out = (float*)d_out;                 // (2048, 1024) fp32

    char* ws = (char*)d_ws;
    auto MB = [](size_t m) { return m << 20; };
    u16*   Uh  = (u16*)(ws + MB(0));
    u16*   Ul  = (u16*)(ws + MB(2));
    u16*   Uth = (u16*)(ws + MB(4));
    u16*   Utl = (u16*)(ws + MB(6));
    u16*   Wh  = (u16*)(ws + MB(8));
    u16*   Wl  = (u16*)(ws + MB(10));
    float* Csc = (float*)(ws + MB(12));          // 8 MB
    u16*   Rah = (u16*)(ws + MB(20));
    u16*   Ral = (u16*)(ws + MB(24));
    u16*   Rbh = (u16*)(ws + MB(28));
    u16*   Rbl = (u16*)(ws + MB(32));            // ends at 36 MB
    u16*   Ih  = Rbh;   // img split lives only until Csc is built
    u16*   Il  = Rbl;

    // ---- prologue ----
    k_split<<<4096, 256, 0, stream>>>(U, Uh, Ul, 1024 * 1024);
    k_split<<<8192, 256, 0, stream>>>(img, Ih, Il, 2048 * 1024);
    k_transpose_split<<<dim3(32, 32), 256, 0, stream>>>(U, Uth, Utl);

    // W = I - 0.2 * U @ U^T
    gemm_ista<2><<<128, 512, 0, stream>>>(Uh, Ul, Uh, Ul, 16,
                                          nullptr, nullptr, Wh, Wl);
    // Csc = 0.2 * img @ U^T ; R1 = st(Csc)
    gemm_ista<1><<<256, 512, 0, stream>>>(Ih, Il, Uh, Ul, 16,
                                          nullptr, Csc, Rah, Ral);

    // ---- iterations 2..150: R <- st(R @ W + Csc), 128 blocks 128^2 tiles ----
    u16 *ch = Rah, *cl = Ral, *nh = Rbh, *nl = Rbl;
    for (int it = 0; it < 149; ++it) {
        gemm_big<0><<<128, 256, 0, stream>>>(ch, cl, Wh, Wl, Csc,
                                             nh, nl, nullptr);
        u16* t;
        t = ch; ch = nh; nh = t;
        t = cl; cl = nl; nl = t;
    }

    // ---- out = R @ U (NT against Ut) ----
    gemm_big<1><<<128, 256, 0, stream>>>(ch, cl, Uth, Utl, nullptr,
                                         nullptr, nullptr, out);
}

// Round 10
// 4993.736 us; speedup vs baseline: 1.1274x; 1.1274x over previous
//
#include <hip/hip_runtime.h>
#include <cstddef>
#include <cstdint>

using f32x4  = __attribute__((ext_vector_type(4))) float;
using bf16x8 = __attribute__((ext_vector_type(8))) short;
using u16x4  = __attribute__((ext_vector_type(4))) unsigned short;
typedef unsigned short u16;

#define LMDA 0.005f

__device__ __forceinline__ u16 f2bf(float f) {
    union { float f; uint32_t u; } v; v.f = f;
    return (u16)((v.u + 0x7FFFu + ((v.u >> 16) & 1u)) >> 16);
}
__device__ __forceinline__ float bf2f(u16 b) {
    union { uint32_t u; float f; } v; v.u = ((uint32_t)b) << 16;
    return v.f;
}
__device__ __forceinline__ void split2(float x, u16& h, u16& l) {
    h = f2bf(x); l = f2bf(x - bf2f(h));
}
__device__ __forceinline__ float sthr(float x) {
    float ax = fabsf(x) - LMDA;
    return ax > 0.0f ? copysignf(ax, x) : 0.0f;
}

// async 16B global -> LDS (HW writes lane l at ldsbase + l*16)
__device__ __forceinline__ void gload16(const u16* g, u16* l) {
    __builtin_amdgcn_global_load_lds(
        (const __attribute__((address_space(1))) unsigned int*)(const void*)g,
        (__attribute__((address_space(3))) unsigned int*)(void*)l, 16, 0, 0);
}

// ---------------------------------------------------------------------------
// ITERATION GEMM, occupancy-first: tile 64m x 128n, split-K 2 (K=512/block),
// grid 512 = 256 tiles x 2 chunks. 256 thr = 4 waves (2mr x 2nc), wavetile
// 32x64 = 2x4 frags of 16x16x32. LDS dbuf 2 x 24 KB = 48 KB -> 3 blocks/CU
// -> 12 waves/CU (the variable rounds 2-9 never moved off 8).
//   acc[mf][nf] = sum_k Wh*Rh + Wl*Rh + Wh*Rl   (swapped operands:
//   mfma(W-frag, R-frag) -> D col(lane&15)=m-local, row(lg*4+e)=n-local)
// BK=32, 16 steps, chunks of 1KB (16 rows x 32 k), lane*16B = linear
// global_load_lds dest + conflict-free ds_read_b128.
// Per step: vmcnt(0); barrier; stage(next); 12 ds_read + 24 MFMA  (m97 form;
// other 2 resident blocks hide the drain).
// Epilogue: fp32 partial store P[chunk] (no cross-block sync; reduce kernel
// combines).
// ---------------------------------------------------------------------------
__global__ __launch_bounds__(256, 3)
void gemm_occ(const u16* __restrict__ Rh, const u16* __restrict__ Rl,
              const u16* __restrict__ Wh, const u16* __restrict__ Wl,
              float* __restrict__ P)
{
    __shared__ __align__(16) u16 S[2][24 * 512];   // 2 x 24 KiB

    // XCD-aware bijective swizzle (512 % 8 == 0)
    const int fid = blockIdx.x;
    const int sid = (fid & 7) * 64 + (fid >> 3);
    const int tile  = sid & 255;          // 0..255
    const int chunk = sid >> 8;           // 0..1
    const int tr = tile >> 3;             // 0..31
    const int tc = tile & 7;              // 0..7
    const int row0 = tr << 6;             // R rows [row0, +64)
    const int col0 = tc << 7;             // n cols [col0, +128)
    const int kb   = chunk << 9;          // k origin (u16 elements)

    const int tid  = threadIdx.x;
    const int lane = tid & 63;
    const int w    = tid >> 6;            // 0..3
    const int mr   = w >> 1;              // m-half
    const int nc   = w & 1;               // n-half
    const int l15  = lane & 15;
    const int lg   = lane >> 4;           // 0..3
    const int l8   = lane << 3;           // u16 offset of lane's 16B

    // ---- staging: 24 chunks of 1KB per step (8 R + 16 W), 6 per wave ----
    // A(R) chunk c in [0,8):  h=c>>2, g=c&3 : rows row0+g*16
    // B(W) chunk c in [8,24): cb=c-8: h=cb>>3, g=cb&7 : cols col0+g*16
    // lane l <- M_h[base_row + (l&15)][k + (l>>4)*8 .. +8)
    const u16* gsrc[6];
    int loff[6];
    #pragma unroll
    for (int t = 0; t < 6; ++t) {
        const int c = w * 6 + t;
        const u16* base;
        int r;
        if (c < 8) {
            const int h = c >> 2, g = c & 3;
            base = h ? Rl : Rh;
            r = row0 + (g << 4) + l15;
        } else {
            const int cb = c - 8;
            const int h = cb >> 3, g = cb & 7;
            base = h ? Wl : Wh;
            r = col0 + (g << 4) + l15;
        }
        gsrc[t] = base + ((size_t)r << 10) + (lg << 3);
        loff[t] = (c << 9) + l8;
    }
    auto stage = [&](int b, int k) {
        #pragma unroll
        for (int t = 0; t < 6; ++t)
            gload16(gsrc[t] + k, &S[b][loff[t]]);
    };

    f32x4 acc[2][4] = {};   // [mf][nf]

    stage(0, kb);

    for (int s = 0; s < 16; ++s) {
        asm volatile("s_waitcnt vmcnt(0)" ::: "memory");
        __builtin_amdgcn_s_barrier();
        asm volatile("" ::: "memory");
        if (s < 15) stage((s + 1) & 1, kb + ((s + 1) << 5));

        const u16* Sb = S[s & 1];
        bf16x8 rh[2], rl[2], wh[4], wl[4];
        #pragma unroll
        for (int mf = 0; mf < 2; ++mf) {
            const int g = (mr << 1) + mf;
            rh[mf] = *(const bf16x8*)&Sb[((0 | g) << 9) + l8];
            rl[mf] = *(const bf16x8*)&Sb[((4 | g) << 9) + l8];
        }
        #pragma unroll
        for (int nf = 0; nf < 4; ++nf) {
            const int g = (nc << 2) + nf;
            wh[nf] = *(const bf16x8*)&Sb[((8  + g) << 9) + l8];
            wl[nf] = *(const bf16x8*)&Sb[((16 + g) << 9) + l8];
        }
        #pragma unroll
        for (int mf = 0; mf < 2; ++mf)
            #pragma unroll
            for (int nf = 0; nf < 4; ++nf) {
                acc[mf][nf] = __builtin_amdgcn_mfma_f32_16x16x32_bf16(wh[nf], rh[mf], acc[mf][nf], 0, 0, 0);
                acc[mf][nf] = __builtin_amdgcn_mfma_f32_16x16x32_bf16(wl[nf], rh[mf], acc[mf][nf], 0, 0, 0);
                acc[mf][nf] = __builtin_amdgcn_mfma_f32_16x16x32_bf16(wh[nf], rl[mf], acc[mf][nf], 0, 0, 0);
            }
        asm volatile("" ::: "memory");
    }

    // ---- partial store (D layout: col=m-local, row=n-local) ----
    float* Pc = P + ((size_t)chunk << 21);   // 2M floats per chunk
    #pragma unroll
    for (int mf = 0; mf < 2; ++mf) {
        #pragma unroll
        for (int nf = 0; nf < 4; ++nf) {
            const int m  = row0 + (mr << 5) + (mf << 4) + l15;
            const int n0 = col0 + (nc << 6) + (nf << 4) + (lg << 2);
            *(f32x4*)&Pc[((size_t)m << 10) + n0] = acc[mf][nf];
        }
    }
}

// ---------------------------------------------------------------------------
// split-K=2 combine + fused epilogue. grid 2048 x 256 (one f32x4 / thread).
// MODE 0: R' = split(st(P0+P1 + Csc))    MODE 1: out = P0+P1
// ---------------------------------------------------------------------------
template<int MODE>
__global__ __launch_bounds__(256)
void k_combine(const float* __restrict__ P, const float* __restrict__ Cs,
               u16* __restrict__ Nh, u16* __restrict__ Nl,
               float* __restrict__ OutF)
{
    const size_t i = ((size_t)blockIdx.x * 256 + threadIdx.x) << 2;
    f32x4 s = *(const f32x4*)&P[i] + *(const f32x4*)&P[(1u << 21) + i];
    if (MODE == 0) {
        const f32x4 cs = *(const f32x4*)&Cs[i];
        u16x4 hv, lv;
        #pragma unroll
        for (int e = 0; e < 4; ++e) {
            u16 hh, ll; split2(sthr(s[e] + cs[e]), hh, ll);
            hv[e] = hh; lv[e] = ll;
        }
        *(u16x4*)&Nh[i] = hv;
        *(u16x4*)&Nl[i] = lv;
    } else {
        *(f32x4*)&OutF[i] = s;
    }
}

// ---------------------------------------------------------------------------
// PROLOGUE GEMM (round-5, passing): fused-3 split-bf16 NT GEMM + epilogues.
// EPI 1: OutF = 0.2*acc ; R = split(st(OutF))   (Csc and R1)
// EPI 2: OutH/L = split(I - 0.2*acc)            (W)
// ---------------------------------------------------------------------------
template<int EPI>
__global__ __launch_bounds__(512, 2)
void gemm_ista(const u16* __restrict__ Ah, const u16* __restrict__ Al,
               const u16* __restrict__ Bh, const u16* __restrict__ Bl,
               int Nt,
               const float* __restrict__ Cs, float* __restrict__ OutF,
               u16* __restrict__ OutH, u16* __restrict__ OutL)
{
    __shared__ __align__(16) u16 S[3][48 * 512];   // 144 KiB

    const int nwg = gridDim.x;
    const int fid = blockIdx.x;
    const int sid = (fid & 7) * (nwg >> 3) + (fid >> 3);
    const int row0 = (sid / Nt) << 7;
    const int col0 = (sid % Nt) << 6;

    const int tid  = threadIdx.x;
    const int lane = tid & 63;
    const int w    = tid >> 6;
    const int mr = w >> 2, nc = (w >> 1) & 1, ks = w & 1;

    const u16* gb[6];
    int cf[6];
    #pragma unroll
    for (int t = 0; t < 6; ++t) {
        const int c = w * 6 + t;
        const u16* base; int r; int kss;
        if (c < 32) {
            const int h = (c >> 4) & 1; kss = (c >> 3) & 1;
            base = h ? Al : Ah;
            r = row0 + ((c & 7) << 4) + (lane & 15);
        } else {
            const int cb = c - 32;
            const int h = (cb >> 3) & 1; kss = (cb >> 2) & 1;
            base = h ? Bl : Bh;
            r = col0 + ((cb & 3) << 4) + (lane & 15);
        }
        gb[t] = base + ((size_t)r << 10) + (kss << 5) + ((lane >> 4) << 3);
        cf[t] = c << 9;
    }
    auto stage = [&](int b, int koff) {
        #pragma unroll
        for (int t = 0; t < 6; ++t)
            gload16(gb[t] + koff, &S[b][cf[t]]);
    };

    f32x4 acc[4][2] = {};

    stage(0, 0);
    stage(1, 64);

    #pragma unroll
    for (int s = 0; s < 16; ++s) {
        if (s <= 14) asm volatile("s_waitcnt vmcnt(6)" ::: "memory");
        else         asm volatile("s_waitcnt vmcnt(0)" ::: "memory");
        __builtin_amdgcn_s_barrier();
        asm volatile("" ::: "memory");
        if (s + 2 < 16) stage((s + 2) % 3, (s + 2) << 6);

        const u16* Sb = S[s % 3];
        const int ab = (ks << 3) + (mr << 2);
        const int bb = 32 + (ks << 2) + (nc << 1);
        bf16x8 ah[4], al[4], bh[2], bl[2];
        #pragma unroll
        for (int i = 0; i < 4; ++i) {
            ah[i] = *(const bf16x8*)&Sb[(ab + i)      * 512 + (lane << 3)];
            al[i] = *(const bf16x8*)&Sb[(ab + 16 + i) * 512 + (lane << 3)];
        }
        #pragma unroll
        for (int j = 0; j < 2; ++j) {
            bh[j] = *(const bf16x8*)&Sb[(bb + j)     * 512 + (lane << 3)];
            bl[j] = *(const bf16x8*)&Sb[(bb + 8 + j) * 512 + (lane << 3)];
        }
        #pragma unroll
        for (int i = 0; i < 4; ++i)
            #pragma unroll
            for (int j = 0; j < 2; ++j)
                acc[i][j] = __builtin_amdgcn_mfma_f32_16x16x32_bf16(ah[i], bh[j], acc[i][j], 0, 0, 0);
        #pragma unroll
        for (int i = 0; i < 4; ++i)
            #pragma unroll
            for (int j = 0; j < 2; ++j)
                acc[i][j] = __builtin_amdgcn_mfma_f32_16x16x32_bf16(al[i], bh[j], acc[i][j], 0, 0, 0);
        #pragma unroll
        for (int i = 0; i < 4; ++i)
            #pragma unroll
            for (int j = 0; j < 2; ++j)
                acc[i][j] = __builtin_amdgcn_mfma_f32_16x16x32_bf16(ah[i], bl[j], acc[i][j], 0, 0, 0);
        asm volatile("" ::: "memory");
    }

    __syncthreads();
    f32x4* red = (f32x4*)&S[0][0];
    const int wquad = (mr << 1) + nc;
    #pragma unroll
    for (int ih = 0; ih < 2; ++ih) {
        #pragma unroll
        for (int j = 0; j < 2; ++j) {
            const int isrc = ks ? ih : (2 + ih);
            const int slot = ((((wquad << 1) | ks) << 2) | (ih << 1) | j);
            red[slot * 64 + lane] = acc[isrc][j];
        }
    }
    __syncthreads();

    const int gr0 = row0 + (mr << 6) + ((lane >> 4) << 2);
    const int gc  = col0 + (nc << 5) + (lane & 15);
    #pragma unroll
    for (int ih = 0; ih < 2; ++ih) {
        #pragma unroll
        for (int j = 0; j < 2; ++j) {
            const int i    = ks ? (2 + ih) : ih;
            const int slot = ((((wquad << 1) | (ks ^ 1)) << 2) | (ih << 1) | j);
            f32x4 sum = acc[i][j] + red[slot * 64 + lane];
            #pragma unroll
            for (int e = 0; e < 4; ++e) {
                const int grow = gr0 + (i << 4) + e;
                const int gcol = gc + (j << 4);
                const size_t idx = ((size_t)grow << 10) + gcol;
                const float p = sum[e];
                if (EPI == 1) {
                    float f = 0.2f * p;
                    OutF[idx] = f;
                    u16 h, l; split2(sthr(f), h, l);
                    OutH[idx] = h; OutL[idx] = l;
                } else {
                    float x = (grow == gcol ? 1.0f : 0.0f) - 0.2f * p;
                    u16 h, l; split2(x, h, l);
                    OutH[idx] = h; OutL[idx] = l;
                }
            }
        }
    }
}

// fp32 -> (hi, lo) bf16 pair, elementwise
__global__ void k_split(const float* __restrict__ in, u16* __restrict__ hi,
                        u16* __restrict__ lo, int n)
{
    int i = blockIdx.x * 256 + threadIdx.x;
    if (i < n) { u16 h, l; split2(in[i], h, l); hi[i] = h; lo[i] = l; }
}

// Ut[j][k] = U[k][j] as bf16 pair (32x32 LDS tile, padded)
__global__ __launch_bounds__(256)
void k_transpose_split(const float* __restrict__ in, u16* __restrict__ hi,
                       u16* __restrict__ lo)
{
    __shared__ float t[32][33];
    const int bx = blockIdx.x, by = blockIdx.y;
    const int lx = threadIdx.x & 31, ly = threadIdx.x >> 5;
    #pragma unroll
    for (int rr = 0; rr < 4; ++rr) {
        int r = ly * 4 + rr;
        t[r][lx] = in[(size_t)(by * 32 + r) * 1024 + bx * 32 + lx];
    }
    __syncthreads();
    #pragma unroll
    for (int rr = 0; rr < 4; ++rr) {
        int r = ly * 4 + rr;
        u16 h, l; split2(t[lx][r], h, l);
        size_t idx = (size_t)(bx * 32 + r) * 1024 + by * 32 + lx;
        hi[idx] = h; lo[idx] = l;
    }
}

extern "C" void kernel_launch(void* const* d_in, const int* in_sizes, int n_in,
                              void* d_out, int out_size, void* d_ws, size_t ws_size,
                              hipStream_t stream) {
    const float* img = (const float*)d_in[0];   // (2048, 1024) fp32
    const float* U   = (const float*)d_in[1];   // (1024, 1024) fp32
    float* out = (float*)d_out;                 // (2048, 1024) fp32

    char* ws = (char*)d_ws;
    auto MB = [](size_t m) { return m << 20; };
    u16*   Uh  = (u16*)(ws + MB(0));
    u16*   Ul  = (u16*)(ws + MB(2));
    u16*   Uth = (u16*)(ws + MB(4));
    u16*   Utl = (u16*)(ws + MB(6));
    u16*   Wh  = (u16*)(ws + MB(8));
    u16*   Wl  = (u16*)(ws + MB(10));
    float* Csc = (float*)(ws + MB(12));          // 8 MB
    u16*   Rah = (u16*)(ws + MB(20));
    u16*   Ral = (u16*)(ws + MB(24));
    u16*   Rbh = (u16*)(ws + MB(28));
    u16*   Rbl = (u16*)(ws + MB(32));            // ends at 36 MB
    float* P   = (float*)(ws + MB(36));          // 16 MB split-K partials
    u16*   Ih  = Rbh;   // img split lives only until Csc is built
    u16*   Il  = Rbl;

    // ---- prologue ----
    k_split<<<4096, 256, 0, stream>>>(U, Uh, Ul, 1024 * 1024);
    k_split<<<8192, 256, 0, stream>>>(img, Ih, Il, 2048 * 1024);
    k_transpose_split<<<dim3(32, 32), 256, 0, stream>>>(U, Uth, Utl);

    // W = I - 0.2 * U @ U^T
    gemm_ista<2><<<128, 512, 0, stream>>>(Uh, Ul, Uh, Ul, 16,
                                          nullptr, nullptr, Wh, Wl);
    // Csc = 0.2 * img @ U^T ; R1 = st(Csc)
    gemm_ista<1><<<256, 512, 0, stream>>>(Ih, Il, Uh, Ul, 16,
                                          nullptr, Csc, Rah, Ral);

    // ---- iterations 2..150: R <- st(R @ W + Csc) ----
    // gemm_occ: 512 blocks (3/CU residency, 12 waves/CU), split-K=2 partials;
    // k_combine: streaming reduce + ISTA epilogue (r3-proven rate).
    u16 *ch = Rah, *cl = Ral, *nh = Rbh, *nl = Rbl;
    for (int it = 0; it < 149; ++it) {
        gemm_occ<<<512, 256, 0, stream>>>(ch, cl, Wh, Wl, P);
        k_combine<0><<<2048, 256, 0, stream>>>(P, Csc, nh, nl, nullptr);
        u16* t;
        t = ch; ch = nh; nh = t;
        t = cl; cl = nl; nl = t;
    }

    // ---- out = R @ U (NT against Ut) ----
    gemm_occ<<<512, 256, 0, stream>>>(ch, cl, Uth, Utl, P);
    k_combine<1><<<2048, 256, 0, stream>>>(P, nullptr, nullptr, nullptr, out);
}

// Round 11
// 4122.186 us; speedup vs baseline: 1.3657x; 1.2114x over previous
//
#include <hip/hip_runtime.h>
#include <cstddef>
#include <cstdint>

using f32x4  = __attribute__((ext_vector_type(4))) float;
using bf16x8 = __attribute__((ext_vector_type(8))) short;
using u16x4  = __attribute__((ext_vector_type(4))) unsigned short;
typedef unsigned short u16;

#define LMDA 0.005f

__device__ __forceinline__ u16 f2bf(float f) {
    union { float f; uint32_t u; } v; v.f = f;
    return (u16)((v.u + 0x7FFFu + ((v.u >> 16) & 1u)) >> 16);
}
__device__ __forceinline__ float bf2f(u16 b) {
    union { uint32_t u; float f; } v; v.u = ((uint32_t)b) << 16;
    return v.f;
}
__device__ __forceinline__ void split2(float x, u16& h, u16& l) {
    h = f2bf(x); l = f2bf(x - bf2f(h));
}
__device__ __forceinline__ float sthr(float x) {
    float ax = fabsf(x) - LMDA;
    return ax > 0.0f ? copysignf(ax, x) : 0.0f;
}

// async 16B global -> LDS (HW writes lane l at ldsbase + l*16)
__device__ __forceinline__ void gload16(const u16* g, u16* l) {
    __builtin_amdgcn_global_load_lds(
        (const __attribute__((address_space(1))) unsigned int*)(const void*)g,
        (__attribute__((address_space(3))) unsigned int*)(void*)l, 16, 0, 0);
}

// ---------------------------------------------------------------------------
// DIAGONAL-FOLDED ITERATION KERNEL.
//   R@W = 0.8*R + R@Wo  (Wo = -0.2*offdiag(U@U^T), SINGLE bf16 matrix, 2 MB)
//   acc[mf][nf] = sum_k (Rh@Woh + Rl@Woh)   [2 products]
// Tile 64m x 128n, grid 256 = 32(tr) x 8(tc) -> traffic-optimal 128 MB/iter,
// Woh L2-resident per XCD. 512 thr = 8 waves (2mr x 4nc), 2 waves/SIMD,
// wavetile 32x32 = 2x2 frags of 16x16x32 (x2 h/l products = 8 MFMA/step).
// BK=32, 32 steps, LDS dbuf 2 x 16KB fragment-ordered 1KB chunks (lane*16B =
// linear global_load_lds dest + conflict-free ds_read_b128).
// Swapped operands mfma(Wo-frag, R-frag): D col(lane&15)=m-local,
// row(lg*4+e)=n-local -> all epilogue accesses contiguous in n.
// OM 0 (ISTA step): R' = split(st(acc + 0.8*(Rh+Rl) + Csc))
// OM 1 (final)    : OutF = acc          (Bm = Ut, out = R@U)
// ---------------------------------------------------------------------------
template<int OM>
__global__ __launch_bounds__(512, 2)
void gemm_diag(const u16* __restrict__ Rh, const u16* __restrict__ Rl,
               const u16* __restrict__ Bm,
               const float* __restrict__ Cs,
               u16* __restrict__ Nh, u16* __restrict__ Nl,
               float* __restrict__ OutF)
{
    __shared__ __align__(16) u16 S[2][16 * 512];   // 2 x 16 KiB

    // XCD-aware bijective swizzle: XCD x gets 4 consecutive tile-rows x all 8
    // col-tiles -> per-XCD read set = Woh(2MB) + R-slab(1MB) + Csc(1MB).
    const int fid = blockIdx.x;
    const int sid = (fid & 7) * 32 + (fid >> 3);
    const int tr = sid >> 3;              // 0..31
    const int tc = sid & 7;               // 0..7
    const int row0 = tr << 6;             // R rows [row0, +64)
    const int col0 = tc << 7;             // n cols [col0, +128)

    const int tid  = threadIdx.x;
    const int lane = tid & 63;
    const int w    = tid >> 6;            // 0..7
    const int mr   = w >> 2;              // 0..1 (m-half)
    const int nc   = w & 3;               // 0..3 (n-quarter)
    const int l15  = lane & 15;
    const int lg   = lane >> 4;           // 0..3
    const int l8   = lane << 3;           // u16 offset of lane's 16B

    // ---- staging: 16 chunks of 1KB per step (4 Rh + 4 Rl + 8 Woh), 2/wave --
    // chunk c<8: h=c>>2, g=c&3: rows row0+g*16 of Rh/Rl
    // chunk c>=8: g=c&7:        rows col0+g*16 of Bm
    // lane l <- M[base_row + (l&15)][k + (l>>4)*8 .. +8)
    const u16* gsrc[2];
    int loff[2];
    #pragma unroll
    for (int t = 0; t < 2; ++t) {
        const int c = (w << 1) + t;
        const u16* base;
        int r;
        if (c < 8) {
            const int h = c >> 2, g = c & 3;
            base = h ? Rl : Rh;
            r = row0 + (g << 4) + l15;
        } else {
            const int g = c & 7;
            base = Bm;
            r = col0 + (g << 4) + l15;
        }
        gsrc[t] = base + ((size_t)r << 10) + (lg << 3);
        loff[t] = (c << 9) + l8;
    }
    auto stage = [&](int b, int k) {
        gload16(gsrc[0] + k, &S[b][loff[0]]);
        gload16(gsrc[1] + k, &S[b][loff[1]]);
    };

    f32x4 acc[2][2] = {};   // [mf][nf]

    stage(0, 0);

    #pragma unroll 8
    for (int s = 0; s < 32; ++s) {
        asm volatile("s_waitcnt vmcnt(0)" ::: "memory");
        __builtin_amdgcn_s_barrier();
        asm volatile("" ::: "memory");
        if (s < 31) stage((s + 1) & 1, (s + 1) << 5);

        const u16* Sb = S[s & 1];
        bf16x8 rh[2], rl[2], wo[2];
        #pragma unroll
        for (int mf = 0; mf < 2; ++mf) {
            const int g = (mr << 1) + mf;
            rh[mf] = *(const bf16x8*)&Sb[((0 + g) << 9) + l8];
            rl[mf] = *(const bf16x8*)&Sb[((4 + g) << 9) + l8];
        }
        #pragma unroll
        for (int nf = 0; nf < 2; ++nf) {
            const int g = (nc << 1) + nf;
            wo[nf] = *(const bf16x8*)&Sb[((8 + g) << 9) + l8];
        }
        #pragma unroll
        for (int mf = 0; mf < 2; ++mf)
            #pragma unroll
            for (int nf = 0; nf < 2; ++nf) {
                acc[mf][nf] = __builtin_amdgcn_mfma_f32_16x16x32_bf16(wo[nf], rh[mf], acc[mf][nf], 0, 0, 0);
                acc[mf][nf] = __builtin_amdgcn_mfma_f32_16x16x32_bf16(wo[nf], rl[mf], acc[mf][nf], 0, 0, 0);
            }
        asm volatile("" ::: "memory");
    }

    // ---- fused epilogue (D layout: col=m-local, row=n-local) ----
    #pragma unroll
    for (int mf = 0; mf < 2; ++mf) {
        #pragma unroll
        for (int nf = 0; nf < 2; ++nf) {
            const int m  = row0 + (mr << 5) + (mf << 4) + l15;
            const int n0 = col0 + (nc << 5) + (nf << 4) + (lg << 2);
            const size_t idx = ((size_t)m << 10) + n0;
            if (OM == 0) {
                const u16x4 rh4 = *(const u16x4*)&Rh[idx];
                const u16x4 rl4 = *(const u16x4*)&Rl[idx];
                const f32x4 cs  = *(const f32x4*)&Cs[idx];
                u16x4 hv, lv;
                #pragma unroll
                for (int e = 0; e < 4; ++e) {
                    float r  = bf2f(rh4[e]) + bf2f(rl4[e]);
                    float x  = acc[mf][nf][e] + 0.8f * r + cs[e];
                    u16 hh, ll; split2(sthr(x), hh, ll);
                    hv[e] = hh; lv[e] = ll;
                }
                *(u16x4*)&Nh[idx] = hv;
                *(u16x4*)&Nl[idx] = lv;
            } else {
                *(f32x4*)&OutF[idx] = acc[mf][nf];
            }
        }
    }
}

// ---------------------------------------------------------------------------
// PROLOGUE GEMM (round-5 machinery, passing): fused-3 split-bf16 NT GEMM.
// EPI 1: OutF = 0.2*acc ; R = split(st(OutF))       (Csc and R1)
// EPI 4: OutH = f2bf(diag? 0 : -0.2*acc)            (Woh, single bf16)
// ---------------------------------------------------------------------------
template<int EPI>
__global__ __launch_bounds__(512, 2)
void gemm_ista(const u16* __restrict__ Ah, const u16* __restrict__ Al,
               const u16* __restrict__ Bh, const u16* __restrict__ Bl,
               int Nt,
               const float* __restrict__ Cs, float* __restrict__ OutF,
               u16* __restrict__ OutH, u16* __restrict__ OutL)
{
    __shared__ __align__(16) u16 S[3][48 * 512];   // 144 KiB

    const int nwg = gridDim.x;
    const int fid = blockIdx.x;
    const int sid = (fid & 7) * (nwg >> 3) + (fid >> 3);
    const int row0 = (sid / Nt) << 7;
    const int col0 = (sid % Nt) << 6;

    const int tid  = threadIdx.x;
    const int lane = tid & 63;
    const int w    = tid >> 6;
    const int mr = w >> 2, nc = (w >> 1) & 1, ks = w & 1;

    const u16* gb[6];
    int cf[6];
    #pragma unroll
    for (int t = 0; t < 6; ++t) {
        const int c = w * 6 + t;
        const u16* base; int r; int kss;
        if (c < 32) {
            const int h = (c >> 4) & 1; kss = (c >> 3) & 1;
            base = h ? Al : Ah;
            r = row0 + ((c & 7) << 4) + (lane & 15);
        } else {
            const int cb = c - 32;
            const int h = (cb >> 3) & 1; kss = (cb >> 2) & 1;
            base = h ? Bl : Bh;
            r = col0 + ((cb & 3) << 4) + (lane & 15);
        }
        gb[t] = base + ((size_t)r << 10) + (kss << 5) + ((lane >> 4) << 3);
        cf[t] = c << 9;
    }
    auto stage = [&](int b, int koff) {
        #pragma unroll
        for (int t = 0; t < 6; ++t)
            gload16(gb[t] + koff, &S[b][cf[t]]);
    };

    f32x4 acc[4][2] = {};

    stage(0, 0);
    stage(1, 64);

    #pragma unroll
    for (int s = 0; s < 16; ++s) {
        if (s <= 14) asm volatile("s_waitcnt vmcnt(6)" ::: "memory");
        else         asm volatile("s_waitcnt vmcnt(0)" ::: "memory");
        __builtin_amdgcn_s_barrier();
        asm volatile("" ::: "memory");
        if (s + 2 < 16) stage((s + 2) % 3, (s + 2) << 6);

        const u16* Sb = S[s % 3];
        const int ab = (ks << 3) + (mr << 2);
        const int bb = 32 + (ks << 2) + (nc << 1);
        bf16x8 ah[4], al[4], bh[2], bl[2];
        #pragma unroll
        for (int i = 0; i < 4; ++i) {
            ah[i] = *(const bf16x8*)&Sb[(ab + i)      * 512 + (lane << 3)];
            al[i] = *(const bf16x8*)&Sb[(ab + 16 + i) * 512 + (lane << 3)];
        }
        #pragma unroll
        for (int j = 0; j < 2; ++j) {
            bh[j] = *(const bf16x8*)&Sb[(bb + j)     * 512 + (lane << 3)];
            bl[j] = *(const bf16x8*)&Sb[(bb + 8 + j) * 512 + (lane << 3)];
        }
        #pragma unroll
        for (int i = 0; i < 4; ++i)
            #pragma unroll
            for (int j = 0; j < 2; ++j)
                acc[i][j] = __builtin_amdgcn_mfma_f32_16x16x32_bf16(ah[i], bh[j], acc[i][j], 0, 0, 0);
        #pragma unroll
        for (int i = 0; i < 4; ++i)
            #pragma unroll
            for (int j = 0; j < 2; ++j)
                acc[i][j] = __builtin_amdgcn_mfma_f32_16x16x32_bf16(al[i], bh[j], acc[i][j], 0, 0, 0);
        #pragma unroll
        for (int i = 0; i < 4; ++i)
            #pragma unroll
            for (int j = 0; j < 2; ++j)
                acc[i][j] = __builtin_amdgcn_mfma_f32_16x16x32_bf16(ah[i], bl[j], acc[i][j], 0, 0, 0);
        asm volatile("" ::: "memory");
    }

    __syncthreads();
    f32x4* red = (f32x4*)&S[0][0];
    const int wquad = (mr << 1) + nc;
    #pragma unroll
    for (int ih = 0; ih < 2; ++ih) {
        #pragma unroll
        for (int j = 0; j < 2; ++j) {
            const int isrc = ks ? ih : (2 + ih);
            const int slot = ((((wquad << 1) | ks) << 2) | (ih << 1) | j);
            red[slot * 64 + lane] = acc[isrc][j];
        }
    }
    __syncthreads();

    const int gr0 = row0 + (mr << 6) + ((lane >> 4) << 2);
    const int gc  = col0 + (nc << 5) + (lane & 15);
    #pragma unroll
    for (int ih = 0; ih < 2; ++ih) {
        #pragma unroll
        for (int j = 0; j < 2; ++j) {
            const int i    = ks ? (2 + ih) : ih;
            const int slot = ((((wquad << 1) | (ks ^ 1)) << 2) | (ih << 1) | j);
            f32x4 sum = acc[i][j] + red[slot * 64 + lane];
            #pragma unroll
            for (int e = 0; e < 4; ++e) {
                const int grow = gr0 + (i << 4) + e;
                const int gcol = gc + (j << 4);
                const size_t idx = ((size_t)grow << 10) + gcol;
                const float p = sum[e];
                if (EPI == 1) {
                    float f = 0.2f * p;
                    OutF[idx] = f;
                    u16 h, l; split2(sthr(f), h, l);
                    OutH[idx] = h; OutL[idx] = l;
                } else {   // EPI 4: Woh = bf16(-0.2*offdiag)
                    float x = (grow == gcol) ? 0.0f : -0.2f * p;
                    OutH[idx] = f2bf(x);
                }
            }
        }
    }
}

// fp32 -> (hi, lo) bf16 pair, elementwise
__global__ void k_split(const float* __restrict__ in, u16* __restrict__ hi,
                        u16* __restrict__ lo, int n)
{
    int i = blockIdx.x * 256 + threadIdx.x;
    if (i < n) { u16 h, l; split2(in[i], h, l); hi[i] = h; lo[i] = l; }
}

// Ut[j][k] = U[k][j] as bf16 (hi used; lo kept for layout compat)
__global__ __launch_bounds__(256)
void k_transpose_split(const float* __restrict__ in, u16* __restrict__ hi,
                       u16* __restrict__ lo)
{
    __shared__ float t[32][33];
    const int bx = blockIdx.x, by = blockIdx.y;
    const int lx = threadIdx.x & 31, ly = threadIdx.x >> 5;
    #pragma unroll
    for (int rr = 0; rr < 4; ++rr) {
        int r = ly * 4 + rr;
        t[r][lx] = in[(size_t)(by * 32 + r) * 1024 + bx * 32 + lx];
    }
    __syncthreads();
    #pragma unroll
    for (int rr = 0; rr < 4; ++rr) {
        int r = ly * 4 + rr;
        u16 h, l; split2(t[lx][r], h, l);
        size_t idx = (size_t)(bx * 32 + r) * 1024 + by * 32 + lx;
        hi[idx] = h; lo[idx] = l;
    }
}

extern "C" void kernel_launch(void* const* d_in, const int* in_sizes, int n_in,
                              void* d_out, int out_size, void* d_ws, size_t ws_size,
                              hipStream_t stream) {
    const float* img = (const float*)d_in[0];   // (2048, 1024) fp32
    const float* U   = (const float*)d_in[1];   // (1024, 1024) fp32
    float* out = (float*)d_out;                 // (2048, 1024) fp32

    char* ws = (char*)d_ws;
    auto MB = [](size_t m) { return m << 20; };
    u16*   Uh  = (u16*)(ws + MB(0));
    u16*   Ul  = (u16*)(ws + MB(2));
    u16*   Uth = (u16*)(ws + MB(4));
    u16*   Utl = (u16*)(ws + MB(6));
    u16*   Woh = (u16*)(ws + MB(8));             // 2 MB single-bf16 offdiag W
    float* Csc = (float*)(ws + MB(12));          // 8 MB
    u16*   Rah = (u16*)(ws + MB(20));
    u16*   Ral = (u16*)(ws + MB(24));
    u16*   Rbh = (u16*)(ws + MB(28));
    u16*   Rbl = (u16*)(ws + MB(32));            // ends at 36 MB
    u16*   Ih  = Rbh;   // img split lives only until Csc is built
    u16*   Il  = Rbl;

    // ---- prologue ----
    k_split<<<4096, 256, 0, stream>>>(U, Uh, Ul, 1024 * 1024);
    k_split<<<8192, 256, 0, stream>>>(img, Ih, Il, 2048 * 1024);
    k_transpose_split<<<dim3(32, 32), 256, 0, stream>>>(U, Uth, Utl);

    // Woh = bf16(-0.2 * offdiag(U @ U^T))
    gemm_ista<4><<<128, 512, 0, stream>>>(Uh, Ul, Uh, Ul, 16,
                                          nullptr, nullptr, Woh, nullptr);
    // Csc = 0.2 * img @ U^T ; R1 = st(Csc)
    gemm_ista<1><<<256, 512, 0, stream>>>(Ih, Il, Uh, Ul, 16,
                                          nullptr, Csc, Rah, Ral);

    // ---- iterations 2..150: R <- st(0.8R + R@Wo + Csc), one kernel/iter ----
    u16 *ch = Rah, *cl = Ral, *nh = Rbh, *nl = Rbl;
    for (int it = 0; it < 149; ++it) {
        gemm_diag<0><<<256, 512, 0, stream>>>(ch, cl, Woh, Csc, nh, nl, nullptr);
        u16* t;
        t = ch; ch = nh; nh = t;
        t = cl; cl = nl; nl = t;
    }

    // ---- out = R @ U (2-product against Ut) ----
    gemm_diag<1><<<256, 512, 0, stream>>>(ch, cl, Uth, nullptr,
                                          nullptr, nullptr, out);
}

// Round 12
// 3423.941 us; speedup vs baseline: 1.6442x; 1.2039x over previous
//
#include <hip/hip_runtime.h>
#include <cstddef>
#include <cstdint>

using f32x4  = __attribute__((ext_vector_type(4))) float;
using bf16x8 = __attribute__((ext_vector_type(8))) short;
using u16x4  = __attribute__((ext_vector_type(4))) unsigned short;
typedef unsigned short u16;

#define LMDA 0.005f

__device__ __forceinline__ u16 f2bf(float f) {
    union { float f; uint32_t u; } v; v.f = f;
    return (u16)((v.u + 0x7FFFu + ((v.u >> 16) & 1u)) >> 16);
}
__device__ __forceinline__ float bf2f(u16 b) {
    union { uint32_t u; float f; } v; v.u = ((uint32_t)b) << 16;
    return v.f;
}
__device__ __forceinline__ void split2(float x, u16& h, u16& l) {
    h = f2bf(x); l = f2bf(x - bf2f(h));
}
__device__ __forceinline__ float sthr(float x) {
    float ax = fabsf(x) - LMDA;
    return ax > 0.0f ? copysignf(ax, x) : 0.0f;
}

// async 16B global -> LDS (HW writes lane l at ldsbase + l*16)
__device__ __forceinline__ void gload16(const u16* g, u16* l) {
    __builtin_amdgcn_global_load_lds(
        (const __attribute__((address_space(1))) unsigned int*)(const void*)g,
        (__attribute__((address_space(3))) unsigned int*)(void*)l, 16, 0, 0);
}

// ---------------------------------------------------------------------------
// SINGLE/DOUBLE-PRODUCT DIAGONAL-FOLDED ITERATION KERNEL.
//   R@W = 0.8*R + R@Wo,  Wo = -0.2*offdiag(U@U^T) as ONE bf16 matrix (2 MB).
//   NPROD=1:  acc = Rh@Bm            (iteration; Rl@Wo dropped — ~1e-4/iter)
//   NPROD=2:  acc = (Rh+Rl)@Bm       (final out = R@U, one-shot accuracy)
// Tile 64m x 128n, grid 256 = 32(tr) x 8(tc), full chip. 512 thr = 8 waves
// (2mr x 4nc), wavetile 32x32 = 2x2 frags of 16x16x32.
// BK=64 -> 16 k-steps (halved barrier/drain count vs r11). LDS dbuf
// 2 x (8*NPROD+16) KB fragment-ordered 1KB chunks (lane*16B = linear
// global_load_lds dest + conflict-free ds_read_b128).
// Swapped operands mfma(B-frag, R-frag): D col(lane&15)=m-local,
// row(lg*4+e)=n-local -> all epilogue accesses contiguous in n.
// OM 0 (ISTA step): R' = split(st(acc + 0.8*(Rh+Rl) + Csc))
// OM 1 (final)    : OutF = acc
// ---------------------------------------------------------------------------
template<int NPROD, int OM>
__global__ __launch_bounds__(512, 2)
void gemm_one(const u16* __restrict__ Rh, const u16* __restrict__ Rl,
              const u16* __restrict__ Bm,
              const float* __restrict__ Cs,
              u16* __restrict__ Nh, u16* __restrict__ Nl,
              float* __restrict__ OutF)
{
    constexpr int NCH = 8 * NPROD + 16;            // chunks per step
    constexpr int CPW = NCH / 8;                   // chunks per wave
    __shared__ __align__(16) u16 S[2][NCH * 512];

    // XCD-aware bijective swizzle: XCD x gets 4 consecutive tile-rows x all 8
    // col-tiles -> per-XCD read set = Woh(2MB) + Rh-slab + Csc-slab.
    const int fid = blockIdx.x;
    const int sid = (fid & 7) * 32 + (fid >> 3);
    const int tr = sid >> 3;              // 0..31
    const int tc = sid & 7;               // 0..7
    const int row0 = tr << 6;             // R rows [row0, +64)
    const int col0 = tc << 7;             // n cols [col0, +128)

    const int tid  = threadIdx.x;
    const int lane = tid & 63;
    const int w    = tid >> 6;            // 0..7
    const int mr   = w >> 2;              // 0..1 (m-half)
    const int nc   = w & 3;               // 0..3 (n-quarter)
    const int l15  = lane & 15;
    const int lg   = lane >> 4;           // 0..3
    const int l8   = lane << 3;           // u16 offset of lane's 16B

    // ---- staging: NCH chunks of 1KB per step, CPW per wave ----
    // A chunk c in [0, 8*NPROD): h=c>>3, kh=(c>>2)&1, g=c&3 :
    //   lane l <- (h?Rl:Rh)[row0+g*16+(l&15)][k0 + kh*32 + (l>>4)*8 .. +8)
    // B chunk c in [8*NPROD, NCH): cb=c-8*NPROD, kh=cb>>3, g=cb&7 :
    //   lane l <- Bm[col0+g*16+(l&15)][k0 + kh*32 + (l>>4)*8 .. +8)
    const u16* gsrc[CPW];
    int loff[CPW];
    #pragma unroll
    for (int t = 0; t < CPW; ++t) {
        const int c = w * CPW + t;
        const u16* base;
        int r, kh;
        if (c < 8 * NPROD) {
            const int h = c >> 3;
            kh = (c >> 2) & 1;
            base = h ? Rl : Rh;
            r = row0 + ((c & 3) << 4) + l15;
        } else {
            const int cb = c - 8 * NPROD;
            kh = cb >> 3;
            base = Bm;
            r = col0 + ((cb & 7) << 4) + l15;
        }
        gsrc[t] = base + ((size_t)r << 10) + (kh << 5) + (lg << 3);
        loff[t] = (c << 9) + l8;
    }
    auto stage = [&](int b, int k) {
        #pragma unroll
        for (int t = 0; t < CPW; ++t)
            gload16(gsrc[t] + k, &S[b][loff[t]]);
    };

    f32x4 acc[2][2] = {};   // [mf][nf]

    stage(0, 0);

    for (int s = 0; s < 16; ++s) {
        asm volatile("s_waitcnt vmcnt(0)" ::: "memory");
        __builtin_amdgcn_s_barrier();
        asm volatile("" ::: "memory");
        if (s < 15) stage((s + 1) & 1, (s + 1) << 6);

        const u16* Sb = S[s & 1];
        bf16x8 rh[2][2], rl[2][2], wo[2][2];
        #pragma unroll
        for (int kh = 0; kh < 2; ++kh) {
            #pragma unroll
            for (int mf = 0; mf < 2; ++mf) {
                const int g = (mr << 1) + mf;
                rh[mf][kh] = *(const bf16x8*)&Sb[(((kh << 2) + g) << 9) + l8];
                if (NPROD == 2)
                    rl[mf][kh] = *(const bf16x8*)&Sb[((8 + (kh << 2) + g) << 9) + l8];
            }
            #pragma unroll
            for (int nf = 0; nf < 2; ++nf) {
                const int g = (nc << 1) + nf;
                wo[nf][kh] = *(const bf16x8*)&Sb[((8 * NPROD + (kh << 3) + g) << 9) + l8];
            }
        }
        #pragma unroll
        for (int kh = 0; kh < 2; ++kh)
            #pragma unroll
            for (int mf = 0; mf < 2; ++mf)
                #pragma unroll
                for (int nf = 0; nf < 2; ++nf) {
                    acc[mf][nf] = __builtin_amdgcn_mfma_f32_16x16x32_bf16(
                        wo[nf][kh], rh[mf][kh], acc[mf][nf], 0, 0, 0);
                    if (NPROD == 2)
                        acc[mf][nf] = __builtin_amdgcn_mfma_f32_16x16x32_bf16(
                            wo[nf][kh], rl[mf][kh], acc[mf][nf], 0, 0, 0);
                }
        asm volatile("" ::: "memory");
    }

    // ---- fused epilogue (D layout: col=m-local, row=n-local) ----
    #pragma unroll
    for (int mf = 0; mf < 2; ++mf) {
        #pragma unroll
        for (int nf = 0; nf < 2; ++nf) {
            const int m  = row0 + (mr << 5) + (mf << 4) + l15;
            const int n0 = col0 + (nc << 5) + (nf << 4) + (lg << 2);
            const size_t idx = ((size_t)m << 10) + n0;
            if (OM == 0) {
                const u16x4 rh4 = *(const u16x4*)&Rh[idx];
                const u16x4 rl4 = *(const u16x4*)&Rl[idx];
                const f32x4 cs  = *(const f32x4*)&Cs[idx];
                u16x4 hv, lv;
                #pragma unroll
                for (int e = 0; e < 4; ++e) {
                    float r  = bf2f(rh4[e]) + bf2f(rl4[e]);
                    float x  = acc[mf][nf][e] + 0.8f * r + cs[e];
                    u16 hh, ll; split2(sthr(x), hh, ll);
                    hv[e] = hh; lv[e] = ll;
                }
                *(u16x4*)&Nh[idx] = hv;
                *(u16x4*)&Nl[idx] = lv;
            } else {
                *(f32x4*)&OutF[idx] = acc[mf][nf];
            }
        }
    }
}

// ---------------------------------------------------------------------------
// PROLOGUE GEMM (round-5 machinery, passing): fused-3 split-bf16 NT GEMM.
// EPI 1: OutF = 0.2*acc ; R = split(st(OutF))       (Csc and R1)
// EPI 4: OutH = f2bf(diag? 0 : -0.2*acc)            (Woh, single bf16)
// ---------------------------------------------------------------------------
template<int EPI>
__global__ __launch_bounds__(512, 2)
void gemm_ista(const u16* __restrict__ Ah, const u16* __restrict__ Al,
               const u16* __restrict__ Bh, const u16* __restrict__ Bl,
               int Nt,
               const float* __restrict__ Cs, float* __restrict__ OutF,
               u16* __restrict__ OutH, u16* __restrict__ OutL)
{
    __shared__ __align__(16) u16 S[3][48 * 512];   // 144 KiB

    const int nwg = gridDim.x;
    const int fid = blockIdx.x;
    const int sid = (fid & 7) * (nwg >> 3) + (fid >> 3);
    const int row0 = (sid / Nt) << 7;
    const int col0 = (sid % Nt) << 6;

    const int tid  = threadIdx.x;
    const int lane = tid & 63;
    const int w    = tid >> 6;
    const int mr = w >> 2, nc = (w >> 1) & 1, ks = w & 1;

    const u16* gb[6];
    int cf[6];
    #pragma unroll
    for (int t = 0; t < 6; ++t) {
        const int c = w * 6 + t;
        const u16* base; int r; int kss;
        if (c < 32) {
            const int h = (c >> 4) & 1; kss = (c >> 3) & 1;
            base = h ? Al : Ah;
            r = row0 + ((c & 7) << 4) + (lane & 15);
        } else {
            const int cb = c - 32;
            const int h = (cb >> 3) & 1; kss = (cb >> 2) & 1;
            base = h ? Bl : Bh;
            r = col0 + ((cb & 3) << 4) + (lane & 15);
        }
        gb[t] = base + ((size_t)r << 10) + (kss << 5) + ((lane >> 4) << 3);
        cf[t] = c << 9;
    }
    auto stage = [&](int b, int koff) {
        #pragma unroll
        for (int t = 0; t < 6; ++t)
            gload16(gb[t] + koff, &S[b][cf[t]]);
    };

    f32x4 acc[4][2] = {};

    stage(0, 0);
    stage(1, 64);

    #pragma unroll
    for (int s = 0; s < 16; ++s) {
        if (s <= 14) asm volatile("s_waitcnt vmcnt(6)" ::: "memory");
        else         asm volatile("s_waitcnt vmcnt(0)" ::: "memory");
        __builtin_amdgcn_s_barrier();
        asm volatile("" ::: "memory");
        if (s + 2 < 16) stage((s + 2) % 3, (s + 2) << 6);

        const u16* Sb = S[s % 3];
        const int ab = (ks << 3) + (mr << 2);
        const int bb = 32 + (ks << 2) + (nc << 1);
        bf16x8 ah[4], al[4], bh[2], bl[2];
        #pragma unroll
        for (int i = 0; i < 4; ++i) {
            ah[i] = *(const bf16x8*)&Sb[(ab + i)      * 512 + (lane << 3)];
            al[i] = *(const bf16x8*)&Sb[(ab + 16 + i) * 512 + (lane << 3)];
        }
        #pragma unroll
        for (int j = 0; j < 2; ++j) {
            bh[j] = *(const bf16x8*)&Sb[(bb + j)     * 512 + (lane << 3)];
            bl[j] = *(const bf16x8*)&Sb[(bb + 8 + j) * 512 + (lane << 3)];
        }
        #pragma unroll
        for (int i = 0; i < 4; ++i)
            #pragma unroll
            for (int j = 0; j < 2; ++j)
                acc[i][j] = __builtin_amdgcn_mfma_f32_16x16x32_bf16(ah[i], bh[j], acc[i][j], 0, 0, 0);
        #pragma unroll
        for (int i = 0; i < 4; ++i)
            #pragma unroll
            for (int j = 0; j < 2; ++j)
                acc[i][j] = __builtin_amdgcn_mfma_f32_16x16x32_bf16(al[i], bh[j], acc[i][j], 0, 0, 0);
        #pragma unroll
        for (int i = 0; i < 4; ++i)
            #pragma unroll
            for (int j = 0; j < 2; ++j)
                acc[i][j] = __builtin_amdgcn_mfma_f32_16x16x32_bf16(ah[i], bl[j], acc[i][j], 0, 0, 0);
        asm volatile("" ::: "memory");
    }

    __syncthreads();
    f32x4* red = (f32x4*)&S[0][0];
    const int wquad = (mr << 1) + nc;
    #pragma unroll
    for (int ih = 0; ih < 2; ++ih) {
        #pragma unroll
        for (int j = 0; j < 2; ++j) {
            const int isrc = ks ? ih : (2 + ih);
            const int slot = ((((wquad << 1) | ks) << 2) | (ih << 1) | j);
            red[slot * 64 + lane] = acc[isrc][j];
        }
    }
    __syncthreads();

    const int gr0 = row0 + (mr << 6) + ((lane >> 4) << 2);
    const int gc  = col0 + (nc << 5) + (lane & 15);
    #pragma unroll
    for (int ih = 0; ih < 2; ++ih) {
        #pragma unroll
        for (int j = 0; j < 2; ++j) {
            const int i    = ks ? (2 + ih) : ih;
            const int slot = ((((wquad << 1) | (ks ^ 1)) << 2) | (ih << 1) | j);
            f32x4 sum = acc[i][j] + red[slot * 64 + lane];
            #pragma unroll
            for (int e = 0; e < 4; ++e) {
                const int grow = gr0 + (i << 4) + e;
                const int gcol = gc + (j << 4);
                const size_t idx = ((size_t)grow << 10) + gcol;
                const float p = sum[e];
                if (EPI == 1) {
                    float f = 0.2f * p;
                    OutF[idx] = f;
                    u16 h, l; split2(sthr(f), h, l);
                    OutH[idx] = h; OutL[idx] = l;
                } else {   // EPI 4: Woh = bf16(-0.2*offdiag)
                    float x = (grow == gcol) ? 0.0f : -0.2f * p;
                    OutH[idx] = f2bf(x);
                }
            }
        }
    }
}

// fp32 -> (hi, lo) bf16 pair, elementwise
__global__ void k_split(const float* __restrict__ in, u16* __restrict__ hi,
                        u16* __restrict__ lo, int n)
{
    int i = blockIdx.x * 256 + threadIdx.x;
    if (i < n) { u16 h, l; split2(in[i], h, l); hi[i] = h; lo[i] = l; }
}

// Ut[j][k] = U[k][j] as bf16 pair
__global__ __launch_bounds__(256)
void k_transpose_split(const float* __restrict__ in, u16* __restrict__ hi,
                       u16* __restrict__ lo)
{
    __shared__ float t[32][33];
    const int bx = blockIdx.x, by = blockIdx.y;
    const int lx = threadIdx.x & 31, ly = threadIdx.x >> 5;
    #pragma unroll
    for (int rr = 0; rr < 4; ++rr) {
        int r = ly * 4 + rr;
        t[r][lx] = in[(size_t)(by * 32 + r) * 1024 + bx * 32 + lx];
    }
    __syncthreads();
    #pragma unroll
    for (int rr = 0; rr < 4; ++rr) {
        int r = ly * 4 + rr;
        u16 h, l; split2(t[lx][r], h, l);
        size_t idx = (size_t)(bx * 32 + r) * 1024 + by * 32 + lx;
        hi[idx] = h; lo[idx] = l;
    }
}

extern "C" void kernel_launch(void* const* d_in, const int* in_sizes, int n_in,
                              void* d_out, int out_size, void* d_ws, size_t ws_size,
                              hipStream_t stream) {
    const float* img = (const float*)d_in[0];   // (2048, 1024) fp32
    const float* U   = (const float*)d_in[1];   // (1024, 1024) fp32
    float* out = (float*)d_out;                 // (2048, 1024) fp32

    char* ws = (char*)d_ws;
    auto MB = [](size_t m) { return m << 20; };
    u16*   Uh  = (u16*)(ws + MB(0));
    u16*   Ul  = (u16*)(ws + MB(2));
    u16*   Uth = (u16*)(ws + MB(4));
    u16*   Utl = (u16*)(ws + MB(6));
    u16*   Woh = (u16*)(ws + MB(8));             // 2 MB single-bf16 offdiag W
    float* Csc = (float*)(ws + MB(12));          // 8 MB
    u16*   Rah = (u16*)(ws + MB(20));
    u16*   Ral = (u16*)(ws + MB(24));
    u16*   Rbh = (u16*)(ws + MB(28));
    u16*   Rbl = (u16*)(ws + MB(32));            // ends at 36 MB
    u16*   Ih  = Rbh;   // img split lives only until Csc is built
    u16*   Il  = Rbl;

    // ---- prologue ----
    k_split<<<4096, 256, 0, stream>>>(U, Uh, Ul, 1024 * 1024);
    k_split<<<8192, 256, 0, stream>>>(img, Ih, Il, 2048 * 1024);
    k_transpose_split<<<dim3(32, 32), 256, 0, stream>>>(U, Uth, Utl);

    // Woh = bf16(-0.2 * offdiag(U @ U^T))
    gemm_ista<4><<<128, 512, 0, stream>>>(Uh, Ul, Uh, Ul, 16,
                                          nullptr, nullptr, Woh, nullptr);
    // Csc = 0.2 * img @ U^T ; R1 = st(Csc)
    gemm_ista<1><<<256, 512, 0, stream>>>(Ih, Il, Uh, Ul, 16,
                                          nullptr, Csc, Rah, Ral);

    // ---- iterations 2..150: R <- st(0.8R + Rh@Wo + Csc), 1 kernel/iter ----
    u16 *ch = Rah, *cl = Ral, *nh = Rbh, *nl = Rbl;
    for (int it = 0; it < 149; ++it) {
        gemm_one<1, 0><<<256, 512, 0, stream>>>(ch, cl, Woh, Csc, nh, nl, nullptr);
        u16* t;
        t = ch; ch = nh; nh = t;
        t = cl; cl = nl; nl = t;
    }

    // ---- out = R @ U (2-product against Ut, one-shot) ----
    gemm_one<2, 1><<<256, 512, 0, stream>>>(ch, cl, Uth, nullptr,
                                            nullptr, nullptr, out);
}